// Round 10
// baseline (675.503 us; speedup 1.0000x reference)
//
#include <hip/hip_runtime.h>

// AttentionModule: 3-layer sigmoid-QKV attention, B=64 N=1024 R=128 D=64 H=64.
// R10 = R8 structure (in-register Q/P via shfl_xor(32) half-wave exchange,
// K/V double-buffered LDS, 1 barrier per K-tile, zero bank conflicts)
//     + R9 XCD-gathering swizzle (blockIdx%8 = XCD; one batch's 8 q-blocks
// share an XCD so its 4MB L2 holds that XCD's 8 batches' K/V; R9 measured
// FETCH 143->24MB). R8's 187us was pure HBM refetch -- now removed.
// Pipeline: prep, xk0 (xpose+K0/V0), flash0(+K1/V1), flash1(+K2/V2), flash2.

typedef __bf16 bf16;
typedef bf16 bf16x2 __attribute__((ext_vector_type(2)));
typedef bf16 bf16x4 __attribute__((ext_vector_type(4)));
typedef bf16 bf16x8 __attribute__((ext_vector_type(8)));
typedef float f32x4 __attribute__((ext_vector_type(4)));
typedef float f32x16 __attribute__((ext_vector_type(16)));

#define MFMA32(a, b, c) __builtin_amdgcn_mfma_f32_32x32x16_bf16(a, b, c, 0, 0, 0)
#define ZERO16 {0,0,0,0,0,0,0,0,0,0,0,0,0,0,0,0}
#define LOG2E 1.44269504f

__device__ __forceinline__ float fast_sigmoid(float x) {
  return __builtin_amdgcn_rcpf(1.0f + exp2f(-LOG2E * x));
}

__device__ __forceinline__ bf16x4 shfl_xor32_b4(bf16x4 v) {
  union { bf16x4 h; int u[2]; } a;
  a.h = v;
  a.u[0] = __shfl_xor(a.u[0], 32, 64);
  a.u[1] = __shfl_xor(a.u[1], 32, 64);
  return a.h;
}
__device__ __forceinline__ bf16x8 cat44(bf16x4 lo, bf16x4 hi4) {
  union { bf16x8 o; bf16x4 p[2]; } u;
  u.p[0] = lo; u.p[1] = hi4;
  return u.o;
}

// ---------------- prep: per-batch scale/bias + weight fp32->bf16 -----------
__global__ __launch_bounds__(256) void prep_kernel(
    const int* __restrict__ L,
    const float* __restrict__ wq0, const float* __restrict__ wqr,
    const float* __restrict__ wk0, const float* __restrict__ wkr,
    const float* __restrict__ wv0, const float* __restrict__ wvr,
    const float* __restrict__ wor, const float* __restrict__ wo_last,
    float* __restrict__ scale_inv, float* __restrict__ biasv,
    bf16* __restrict__ wbf) {
  __shared__ int red[256];
  const int blk = blockIdx.x;
  const int tid = threadIdx.x;
  if (blk < 64) {
    int cnt = 0;
    for (int n = tid; n < 1024; n += 256) cnt += (L[blk * 1024 + n] >= 1) ? 1 : 0;
    red[tid] = cnt;
    __syncthreads();
    for (int s = 128; s > 0; s >>= 1) {
      if (tid < s) red[tid] += red[tid + s];
      __syncthreads();
    }
    if (tid == 0) {
      float iv = rsqrtf((float)red[0] + 1.0f);
      scale_inv[blk] = iv;
      biasv[blk] = fmaxf(0.0f, 128.0f * iv * LOG2E - 80.0f);
    }
  } else {
    for (int i = (blk - 64) * 256 + tid; i < 163840; i += 64 * 256) {
      float v;
      if      (i <   8192) v = wq0[i];
      else if (i <  40960) v = wqr[i - 8192];
      else if (i <  49152) v = wk0[i - 40960];
      else if (i <  81920) v = wkr[i - 49152];
      else if (i <  90112) v = wv0[i - 81920];
      else if (i < 122880) v = wvr[i - 90112];
      else if (i < 155648) v = wor[i - 122880];
      else                 v = wo_last[i - 155648];
      wbf[i] = (bf16)v;
    }
  }
}

// ------------- xk0: transpose x tile + layer-0 K/V for same tokens ---------
__global__ __launch_bounds__(256) void xk0_kernel(
    const float* __restrict__ x, const bf16* __restrict__ Wk,
    const bf16* __restrict__ Wv, bf16* __restrict__ xT,
    bf16* __restrict__ Kt, bf16* __restrict__ Vn) {
  __shared__ float tile[64][65];
  __shared__ __attribute__((aligned(16))) bf16 inp_lds[64 * 72];
  const int tid = threadIdx.x;
  const int lane = tid & 63, wv = tid >> 6;
  const int la = lane & 31, hi = lane >> 5;
  const int b = blockIdx.x >> 4;
  const int t0 = (blockIdx.x & 15) * 64;

  {
    const int nl = tid & 63, dbase = (tid >> 6) * 16;
#pragma unroll
    for (int i = 0; i < 16; i++) {
      int d = dbase + i;
      tile[d][nl] = x[(size_t)(b * 64 + d) * 1024 + t0 + nl];
    }
  }
  __syncthreads();
  {
    const int dl = (tid & 31) * 2, nb = (tid >> 5) * 8;
#pragma unroll
    for (int i = 0; i < 8; i++) {
      int n = nb + i;
      bf16x2 pr = {(bf16)tile[dl][n], (bf16)tile[dl + 1][n]};
      *(bf16x2*)(xT + (size_t)(b * 1024 + t0 + n) * 64 + dl) = pr;
      *(bf16x2*)&inp_lds[n * 72 + dl] = pr;
    }
  }
  __syncthreads();

  const int sub = wv & 1;
  if (wv < 2) {
#pragma unroll
    for (int rt2 = 0; rt2 < 2; rt2++) {
      const int rt = 2 * sub + rt2;
      bf16x8 wf[4];
#pragma unroll
      for (int ks = 0; ks < 4; ks++)
        wf[ks] = *(const bf16x8*)(Wk + (size_t)(la + 32 * rt) * 64 + hi * 8 + ks * 16);
#pragma unroll
      for (int tt = 0; tt < 2; tt++) {
        f32x16 acc = ZERO16;
#pragma unroll
        for (int ks = 0; ks < 4; ks++) {
          bf16x8 bfr = *(const bf16x8*)&inp_lds[(la + 32 * tt) * 72 + hi * 8 + ks * 16];
          acc = MFMA32(wf[ks], bfr, acc);
        }
#pragma unroll
        for (int g = 0; g < 4; g++) {
          bf16x4 pk;
#pragma unroll
          for (int i = 0; i < 4; i++) pk[i] = (bf16)fast_sigmoid(acc[4 * g + i]);
          *(bf16x4*)(Kt + (size_t)(b * 1024 + t0 + 32 * tt + la) * 128 +
                     32 * rt + 8 * g + 4 * hi) = pk;
        }
      }
    }
  } else {
#pragma unroll
    for (int rc2 = 0; rc2 < 2; rc2++) {
      const int rc = 2 * sub + rc2;
      bf16x8 wf[4];
#pragma unroll
      for (int ks = 0; ks < 4; ks++)
        wf[ks] = *(const bf16x8*)(Wv + (size_t)(la + 32 * rc) * 64 + hi * 8 + ks * 16);
#pragma unroll
      for (int tt = 0; tt < 2; tt++) {
        f32x16 acc = ZERO16;
#pragma unroll
        for (int ks = 0; ks < 4; ks++) {
          bf16x8 afr = *(const bf16x8*)&inp_lds[(la + 32 * tt) * 72 + hi * 8 + ks * 16];
          acc = MFMA32(afr, wf[ks], acc);
        }
#pragma unroll
        for (int g = 0; g < 4; g++) {
          bf16x4 pk;
#pragma unroll
          for (int i = 0; i < 4; i++) pk[i] = (bf16)fast_sigmoid(acc[4 * g + i]);
          *(bf16x4*)(Vn + (size_t)(b * 128 + la + 32 * rc) * 1024 +
                     t0 + 32 * tt + 8 * g + 4 * hi) = pk;
        }
      }
    }
  }
}

// -------- standalone KV producer (fallback path only), 64 tokens/block -----
template <int DIN>
__global__ __launch_bounds__(256) void kv_kernel(
    const bf16* __restrict__ inpT, const bf16* __restrict__ Wk,
    const bf16* __restrict__ Wv, bf16* __restrict__ Kt,
    bf16* __restrict__ Vn) {
  constexpr int SIN = DIN + 8;
  constexpr int KS = DIN / 16;
  constexpr int CPR = DIN / 8;
  __shared__ __attribute__((aligned(16))) bf16 inp_lds[64 * SIN];
  const int tid = threadIdx.x;
  const int lane = tid & 63, wv = tid >> 6;
  const int la = lane & 31, hi = lane >> 5;
  const int b = blockIdx.x >> 4;
  const int t0 = (blockIdx.x & 15) * 64;

  for (int i = tid; i < 64 * CPR; i += 256) {
    int row = i / CPR, c = i % CPR;
    *(bf16x8*)&inp_lds[row * SIN + c * 8] =
        *(const bf16x8*)(inpT + (size_t)(b * 1024 + t0 + row) * DIN + c * 8);
  }
  __syncthreads();

  const int sub = wv & 1;
  if (wv < 2) {
#pragma unroll
    for (int rt2 = 0; rt2 < 2; rt2++) {
      const int rt = 2 * sub + rt2;
      bf16x8 wf[KS];
#pragma unroll
      for (int ks = 0; ks < KS; ks++)
        wf[ks] = *(const bf16x8*)(Wk + (size_t)(la + 32 * rt) * DIN + hi * 8 + ks * 16);
#pragma unroll
      for (int tt = 0; tt < 2; tt++) {
        f32x16 acc = ZERO16;
#pragma unroll
        for (int ks = 0; ks < KS; ks++) {
          bf16x8 bfr = *(const bf16x8*)&inp_lds[(la + 32 * tt) * SIN + hi * 8 + ks * 16];
          acc = MFMA32(wf[ks], bfr, acc);
        }
#pragma unroll
        for (int g = 0; g < 4; g++) {
          bf16x4 pk;
#pragma unroll
          for (int i = 0; i < 4; i++) pk[i] = (bf16)fast_sigmoid(acc[4 * g + i]);
          *(bf16x4*)(Kt + (size_t)(b * 1024 + t0 + 32 * tt + la) * 128 +
                     32 * rt + 8 * g + 4 * hi) = pk;
        }
      }
    }
  } else {
#pragma unroll
    for (int rc2 = 0; rc2 < 2; rc2++) {
      const int rc = 2 * sub + rc2;
      bf16x8 wf[KS];
#pragma unroll
      for (int ks = 0; ks < KS; ks++)
        wf[ks] = *(const bf16x8*)(Wv + (size_t)(la + 32 * rc) * DIN + hi * 8 + ks * 16);
#pragma unroll
      for (int tt = 0; tt < 2; tt++) {
        f32x16 acc = ZERO16;
#pragma unroll
        for (int ks = 0; ks < KS; ks++) {
          bf16x8 afr = *(const bf16x8*)&inp_lds[(la + 32 * tt) * SIN + hi * 8 + ks * 16];
          acc = MFMA32(afr, wf[ks], acc);
        }
#pragma unroll
        for (int g = 0; g < 4; g++) {
          bf16x4 pk;
#pragma unroll
          for (int i = 0; i < 4; i++) pk[i] = (bf16)fast_sigmoid(acc[4 * g + i]);
          *(bf16x4*)(Vn + (size_t)(b * 128 + la + 32 * rc) * 1024 +
                     t0 + 32 * tt + 8 * g + 4 * hi) = pk;
        }
      }
    }
  }
}

// ---------------- flash: Q-gen + attention + projection (+ next K/V) -------
// Block: 128 Q rows, 4 waves, grid 512 (2 blocks/CU). Wave wv owns
// n-slice 32*wv for S/PV (Q and P fragments in-register via shfl_xor(32)).
// LDS (elem offsets): K0@0 K1@8448 V0@16896 V1@25600 (strides 132/68).
// XCD swizzle: b = (blockIdx&7)*8 + ((blockIdx>>3)&7), q0 = (blockIdx>>6)*128.
template <int DIN>
__global__ __launch_bounds__(256, 2) void flash_kernel(
    const bf16* __restrict__ inpT, const bf16* __restrict__ Wq,
    const bf16* __restrict__ Kt, const bf16* __restrict__ Vn,
    const float* __restrict__ scale_inv, const float* __restrict__ biasv,
    const int* __restrict__ L, const bf16* __restrict__ Wo,
    void* __restrict__ outp, int last,
    const bf16* __restrict__ Wkn, const bf16* __restrict__ Wvn,
    bf16* __restrict__ Ktn, bf16* __restrict__ Vnn, int kvgen) {
  __shared__ __attribute__((aligned(16))) bf16 smem[34304];  // 68608 B

  const int tid = threadIdx.x;
  const int lane = tid & 63, wv = tid >> 6;
  const int la = lane & 31, hi = lane >> 5;
  const int xcd = blockIdx.x & 7;
  const int kk = blockIdx.x >> 3;
  const int b = xcd * 8 + (kk & 7);
  const int q0 = (kk >> 3) * 128;

  const float inv2 = scale_inv[b] * LOG2E;
  const float bb = biasv[b];

  // ---- stage inp (128 x DIN) ----
  {
    constexpr int SIN = DIN + 8;
    constexpr int CPR = DIN / 8;
    for (int i = tid; i < 128 * CPR; i += 256) {
      int row = i / CPR, c = i % CPR;
      *(bf16x8*)&smem[row * SIN + c * 8] =
          *(const bf16x8*)(inpT + (size_t)(b * 1024 + q0 + row) * DIN + c * 8);
    }
  }
  __syncthreads();

  // first K/V tile prefetch (global latency hides under Q-gen)
  const int krow = tid >> 4, kc = (tid & 15) * 8;
  const int vrow = tid >> 3, vc = (tid & 7) * 8;
  const bf16* kbase = Kt + (size_t)b * 1024 * 128;
  const bf16* vbase = Vn + (size_t)b * 128 * 1024;
  bf16x8 kr[4], vr[4];
#pragma unroll
  for (int p = 0; p < 4; p++) {
    kr[p] = *(const bf16x8*)(kbase + (size_t)(krow + 16 * p) * 128 + kc);
    vr[p] = *(const bf16x8*)(vbase + (size_t)(vrow + 32 * p) * 1024 + vc);
  }

  // ---- Q-gen fully in registers: wave computes its n-slice (32*wv), all r.
  // C-tile (rows r-local, col n=la) -> B-operand frags via shfl_xor(32).
  bf16x8 qB[8];
  {
    constexpr int SIN = DIN + 8;
    constexpr int KSD = DIN / 16;
    bf16x8 ib[KSD];
#pragma unroll
    for (int ks = 0; ks < KSD; ks++)
      ib[ks] = *(const bf16x8*)&smem[(32 * wv + la) * SIN + hi * 8 + ks * 16];
#pragma unroll
    for (int rq = 0; rq < 4; rq++) {
      f32x16 acc = ZERO16;
#pragma unroll
      for (int ks = 0; ks < KSD; ks++) {
        bf16x8 wf = *(const bf16x8*)(Wq + (size_t)(32 * rq + la) * DIN +
                                     hi * 8 + ks * 16);
        acc = MFMA32(wf, ib[ks], acc);
      }
      bf16x4 pg[4];
#pragma unroll
      for (int g = 0; g < 4; g++)
#pragma unroll
        for (int i = 0; i < 4; i++)
          pg[g][i] = (bf16)(fast_sigmoid(acc[4 * g + i]) * inv2);
#pragma unroll
      for (int s = 0; s < 2; s++) {
        bf16x4 mine = hi ? pg[2 * s + 1] : pg[2 * s];
        bf16x4 send = hi ? pg[2 * s] : pg[2 * s + 1];
        bf16x4 recv = shfl_xor32_b4(send);
        qB[2 * rq + s] = hi ? cat44(recv, mine) : cat44(mine, recv);
      }
    }
  }
  __syncthreads();  // inp reads done; K/V buffer writes may begin

  f32x16 acc_o[4] = {ZERO16, ZERO16, ZERO16, ZERO16};
  float rs = 0.f;

  auto computeT = [&](int koff, int voff) {
    const bf16* Ks = smem + koff;
    const bf16* Vs = smem + voff;
    bf16x8 pf[4];
#pragma unroll
    for (int mt = 0; mt < 2; mt++) {
      f32x16 sa = ZERO16;
#pragma unroll
      for (int ks = 0; ks < 8; ks++) {
        bf16x8 kf = *(const bf16x8*)&Ks[(32 * mt + la) * 132 + hi * 8 + ks * 16];
        sa = MFMA32(kf, qB[ks], sa);
      }
      bf16x4 pg[4];
#pragma unroll
      for (int g = 0; g < 4; g++)
#pragma unroll
        for (int i = 0; i < 4; i++) {
          float p = exp2f(sa[4 * g + i] - bb);
          rs += p;
          pg[g][i] = (bf16)p;
        }
#pragma unroll
      for (int s = 0; s < 2; s++) {
        bf16x4 mine = hi ? pg[2 * s + 1] : pg[2 * s];
        bf16x4 send = hi ? pg[2 * s] : pg[2 * s + 1];
        bf16x4 recv = shfl_xor32_b4(send);
        pf[2 * mt + s] = hi ? cat44(recv, mine) : cat44(mine, recv);
      }
    }
#pragma unroll
    for (int rt = 0; rt < 4; rt++)
#pragma unroll
      for (int k2 = 0; k2 < 4; k2++) {
        bf16x8 vB = *(const bf16x8*)&Vs[(32 * rt + la) * 68 + hi * 8 + k2 * 16];
        acc_o[rt] = MFMA32(pf[k2], vB, acc_o[rt]);
      }
  };

  // pipelined loop: stage tile it into buf[it&1], compute tile it-1, 1 barrier
  for (int it = 0; it < 16; it++) {
    const int wb2 = it & 1;
    bf16* Kw = smem + wb2 * 8448;
    bf16* Vw = smem + 16896 + wb2 * 8704;
#pragma unroll
    for (int p = 0; p < 4; p++)
      *(bf16x8*)&Kw[(krow + 16 * p) * 132 + kc] = kr[p];
#pragma unroll
    for (int p = 0; p < 4; p++)
      *(bf16x8*)&Vw[(vrow + 32 * p) * 68 + vc] = vr[p];
    if (it < 15) {
      const int m1 = (it + 1) * 64;
#pragma unroll
      for (int p = 0; p < 4; p++) {
        kr[p] = *(const bf16x8*)(kbase + (size_t)(m1 + krow + 16 * p) * 128 + kc);
        vr[p] = *(const bf16x8*)(vbase + (size_t)(vrow + 32 * p) * 1024 + m1 + vc);
      }
    }
    if (it > 0) computeT((wb2 ^ 1) * 8448, 16896 + (wb2 ^ 1) * 8704);
    __syncthreads();
  }
  computeT(8448, 25600);  // tile 15

  // ---- epilogue: rowsums via shfl, normalize into O_lds, project ----
  float rsf = rs + __shfl_xor(rs, 32, 64);  // lane la: full sum for n=32wv+la
  __syncthreads();  // all K/V reads done before O overwrite
  bf16* O_lds = smem;  // 128 x 132, [n][r]
#pragma unroll
  for (int g = 0; g < 4; g++) {
#pragma unroll
    for (int i = 0; i < 4; i++) {
      float is = 1.0f / __shfl(rsf, 8 * g + 4 * hi + i, 64);
      const int nrow = 32 * wv + 8 * g + 4 * hi + i;
#pragma unroll
      for (int rt = 0; rt < 4; rt++)
        O_lds[(size_t)nrow * 132 + 32 * rt + la] =
            (bf16)(acc_o[rt][4 * g + i] * is);
    }
  }
  __syncthreads();  // O complete

  if (!last) {
    bf16* out_b = (bf16*)outp;
    const int* Lg = L + b * 1024 + q0;
    bf16x8 wB[8];
#pragma unroll
    for (int ks = 0; ks < 8; ks++)
      wB[ks] = *(const bf16x8*)(Wo + (size_t)(la + 32 * wv) * 128 + hi * 8 + ks * 16);
    f32x16 accp[4];
#pragma unroll
    for (int nt = 0; nt < 4; nt++) {
      accp[nt] = ZERO16;
#pragma unroll
      for (int ks = 0; ks < 8; ks++) {
        bf16x8 oA = *(const bf16x8*)&O_lds[(size_t)(la + 32 * nt) * 132 +
                                           hi * 8 + ks * 16];
        accp[nt] = MFMA32(oA, wB[ks], accp[nt]);
      }
    }
    if (kvgen) __syncthreads();  // all O_lds reads done before O2 overwrite
#pragma unroll
    for (int nt = 0; nt < 4; nt++) {
#pragma unroll
      for (int g = 0; g < 4; g++) {
#pragma unroll
        for (int i = 0; i < 4; i++) {
          int n = 32 * nt + 8 * g + 4 * hi + i;
          float xv = accp[nt][4 * g + i];
          float y = xv * fast_sigmoid(xv) * (float)Lg[n];
          out_b[(size_t)(b * 1024 + q0 + n) * 128 + 32 * wv + la] = (bf16)y;
          if (kvgen) O_lds[(size_t)n * 132 + 32 * wv + la] = (bf16)y;  // O2
        }
      }
    }
    if (kvgen) {
      __syncthreads();  // O2 complete
      const bf16* O2 = O_lds;
      const int sub = wv & 1;
      const bf16* W2 = (wv < 2) ? Wkn : Wvn;
#pragma unroll
      for (int rt2 = 0; rt2 < 2; rt2++) {
        const int rt = 2 * sub + rt2;
        bf16x8 wf[8];
#pragma unroll
        for (int ks = 0; ks < 8; ks++)
          wf[ks] = *(const bf16x8*)(W2 + (size_t)(la + 32 * rt) * 128 +
                                    hi * 8 + ks * 16);
#pragma unroll
        for (int tt = 0; tt < 4; tt++) {
          f32x16 acc = ZERO16;
          if (wv < 2) {
#pragma unroll
            for (int ks = 0; ks < 8; ks++) {
              bf16x8 bB = *(const bf16x8*)&O2[(size_t)(32 * tt + la) * 132 +
                                              hi * 8 + ks * 16];
              acc = MFMA32(wf[ks], bB, acc);
            }
#pragma unroll
            for (int g = 0; g < 4; g++) {
              bf16x4 pk;
#pragma unroll
              for (int i = 0; i < 4; i++) pk[i] = (bf16)fast_sigmoid(acc[4 * g + i]);
              *(bf16x4*)(Ktn + (size_t)(b * 1024 + q0 + 32 * tt + la) * 128 +
                         32 * rt + 8 * g + 4 * hi) = pk;
            }
          } else {
#pragma unroll
            for (int ks = 0; ks < 8; ks++) {
              bf16x8 aA = *(const bf16x8*)&O2[(size_t)(32 * tt + la) * 132 +
                                              hi * 8 + ks * 16];
              acc = MFMA32(aA, wf[ks], acc);
            }
#pragma unroll
            for (int g = 0; g < 4; g++) {
              bf16x4 pk;
#pragma unroll
              for (int i = 0; i < 4; i++) pk[i] = (bf16)fast_sigmoid(acc[4 * g + i]);
              *(bf16x4*)(Vnn + (size_t)(b * 128 + 32 * rt + la) * 1024 +
                         q0 + 32 * tt + 8 * g + 4 * hi) = pk;
            }
          }
        }
      }
    }
  } else {
    const int hs = wv & 1, nq = wv >> 1;
    float* outf = (float*)outp;
    bf16x8 wA[8];
#pragma unroll
    for (int ks = 0; ks < 8; ks++)
      wA[ks] = *(const bf16x8*)(Wo + (size_t)(la + 32 * hs) * 128 + hi * 8 + ks * 16);
#pragma unroll
    for (int t = 0; t < 2; t++) {
      const int ns4 = nq + 2 * t;
      f32x16 acc = ZERO16;
#pragma unroll
      for (int ks = 0; ks < 8; ks++) {
        bf16x8 oB = *(const bf16x8*)&O_lds[(size_t)(32 * ns4 + la) * 132 +
                                           hi * 8 + ks * 16];
        acc = MFMA32(wA[ks], oB, acc);
      }
#pragma unroll
      for (int g = 0; g < 4; g++) {
#pragma unroll
        for (int i = 0; i < 4; i++) {
          int h = 32 * hs + 8 * g + 4 * hi + i;
          float xv = acc[4 * g + i];
          outf[(size_t)(b * 64 + h) * 1024 + q0 + 32 * ns4 + la] =
              xv * fast_sigmoid(xv);
        }
      }
    }
  }
}

// ---------------- transpose x (fallback path) ------------------------------
__global__ __launch_bounds__(256) void xpose_kernel(const float* __restrict__ x,
                                                    bf16* __restrict__ xT) {
  __shared__ float tile[64][65];
  const int blk = blockIdx.x;
  const int b = blk >> 4;
  const int n0 = (blk & 15) * 64;
  const int tid = threadIdx.x;
  {
    const int nl = tid & 63, dbase = (tid >> 6) * 16;
#pragma unroll
    for (int i = 0; i < 16; i++) {
      int d = dbase + i;
      tile[d][nl] = x[(size_t)(b * 64 + d) * 1024 + n0 + nl];
    }
  }
  __syncthreads();
  {
    const int dl = (tid & 31) * 2, nb = (tid >> 5) * 8;
#pragma unroll
    for (int i = 0; i < 8; i++) {
      int n = nb + i;
      bf16x2 pr = {(bf16)tile[dl][n], (bf16)tile[dl + 1][n]};
      *(bf16x2*)(xT + (size_t)(b * 1024 + n0 + n) * 64 + dl) = pr;
    }
  }
}

// ---------------- host launch ----------------
extern "C" void kernel_launch(void* const* d_in, const int* in_sizes, int n_in,
                              void* d_out, int out_size, void* d_ws, size_t ws_size,
                              hipStream_t stream) {
  const float* x = (const float*)d_in[0];
  const int* L = (const int*)d_in[1];
  const float* wq0 = (const float*)d_in[2];
  const float* wqr = (const float*)d_in[3];
  const float* wk0 = (const float*)d_in[4];
  const float* wkr = (const float*)d_in[5];
  const float* wv0 = (const float*)d_in[6];
  const float* wvr = (const float*)d_in[7];
  const float* wor = (const float*)d_in[8];
  const float* wo_last = (const float*)d_in[9];

  char* ws = (char*)d_ws;
  float* scale_inv = (float*)(ws + 0);
  float* biasv = (float*)(ws + 1024);
  bf16* wbf = (bf16*)(ws + 4096);
  bf16* xT = (bf16*)(ws + 335872);
  bf16* inpT = (bf16*)(ws + 8724480);
  bf16* KtA = (bf16*)(ws + 25501696);
  bf16* VnA = (bf16*)(ws + 42278912);
  bf16* KtB = (bf16*)(ws + 59056128);
  bf16* VnB = (bf16*)(ws + 75833344);
  // bf16 weight offsets: wq0@0 wqr@8192 wk0@40960 wkr@49152 wv0@81920
  //                      wvr@90112 wor@122880 wo_last@155648

  prep_kernel<<<128, 256, 0, stream>>>(L, wq0, wqr, wk0, wkr, wv0, wvr, wor,
                                       wo_last, scale_inv, biasv, wbf);

  if (ws_size >= 92610560) {
    xk0_kernel<<<1024, 256, 0, stream>>>(x, wbf + 40960, wbf + 81920, xT, KtA, VnA);
    flash_kernel<64><<<512, 256, 0, stream>>>(
        xT, wbf + 0, KtA, VnA, scale_inv, biasv, L, wbf + 122880, (void*)inpT, 0,
        wbf + 49152, wbf + 90112, KtB, VnB, 1);
    flash_kernel<128><<<512, 256, 0, stream>>>(
        inpT, wbf + 8192, KtB, VnB, scale_inv, biasv, L, wbf + 139264,
        (void*)inpT, 0, wbf + 65536, wbf + 106496, KtA, VnA, 1);
    flash_kernel<128><<<512, 256, 0, stream>>>(
        inpT, wbf + 24576, KtA, VnA, scale_inv, biasv, L, wbf + 155648, d_out, 1,
        nullptr, nullptr, nullptr, nullptr, 0);
  } else if (ws_size >= 59056128) {
    xpose_kernel<<<1024, 256, 0, stream>>>(x, xT);
    for (int l = 0; l < 3; l++) {
      const bf16* Wq = (l == 0) ? wbf + 0 : wbf + 8192 + (size_t)(l - 1) * 16384;
      const bf16* Wk = (l == 0) ? wbf + 40960 : wbf + 49152 + (size_t)(l - 1) * 16384;
      const bf16* Wv = (l == 0) ? wbf + 81920 : wbf + 90112 + (size_t)(l - 1) * 16384;
      const bf16* Wo = (l < 2) ? wbf + 122880 + (size_t)l * 16384 : wbf + 155648;
      void* outp = (l < 2) ? (void*)inpT : (void*)d_out;
      if (l == 0) {
        kv_kernel<64><<<1024, 256, 0, stream>>>(xT, Wk, Wv, KtA, VnA);
        flash_kernel<64><<<512, 256, 0, stream>>>(xT, Wq, KtA, VnA, scale_inv,
                                                  biasv, L, Wo, outp, 0,
                                                  nullptr, nullptr, nullptr,
                                                  nullptr, 0);
      } else {
        kv_kernel<128><<<1024, 256, 0, stream>>>(inpT, Wk, Wv, KtA, VnA);
        flash_kernel<128><<<512, 256, 0, stream>>>(inpT, Wq, KtA, VnA, scale_inv,
                                                   biasv, L, Wo, outp,
                                                   (l == 2) ? 1 : 0, nullptr,
                                                   nullptr, nullptr, nullptr, 0);
      }
    }
  }
}

// Round 11
// 268.271 us; speedup vs baseline: 2.5180x; 2.5180x over previous
//
#include <hip/hip_runtime.h>

// AttentionModule: 3-layer sigmoid-QKV attention, B=64 N=1024 R=128 D=64 H=64.
// R11 = R9 exactly (best validated: 305us; R6 3-barrier flash loop + XCD
// swizzle, FETCH 143->24MB) + native v_exp_f32 via __builtin_amdgcn_exp2f
// (exp2f without -ffast-math expands to libm fixup sequence; P-phase issues
// 512 exp2/thread). R8/R10 single-barrier structure abandoned: R10 proved it
// stalls identically with or without HBM traffic (205us @ 25MB fetch).
// Pipeline: prep, xk0 (xpose+K0/V0), flash0(+K1/V1), flash1(+K2/V2), flash2.

typedef __bf16 bf16;
typedef bf16 bf16x2 __attribute__((ext_vector_type(2)));
typedef bf16 bf16x4 __attribute__((ext_vector_type(4)));
typedef bf16 bf16x8 __attribute__((ext_vector_type(8)));
typedef float f32x4 __attribute__((ext_vector_type(4)));
typedef float f32x16 __attribute__((ext_vector_type(16)));

#define MFMA32(a, b, c) __builtin_amdgcn_mfma_f32_32x32x16_bf16(a, b, c, 0, 0, 0)
#define ZERO16 {0,0,0,0,0,0,0,0,0,0,0,0,0,0,0,0}
#define LOG2E 1.44269504f

__device__ __forceinline__ float fast_exp2(float x) {
  return __builtin_amdgcn_exp2f(x);  // v_exp_f32: 2^x, single instruction
}
__device__ __forceinline__ float fast_sigmoid(float x) {
  return __builtin_amdgcn_rcpf(1.0f + fast_exp2(-LOG2E * x));
}

// ---------------- prep: per-batch scale/bias + weight fp32->bf16 -----------
__global__ __launch_bounds__(256) void prep_kernel(
    const int* __restrict__ L,
    const float* __restrict__ wq0, const float* __restrict__ wqr,
    const float* __restrict__ wk0, const float* __restrict__ wkr,
    const float* __restrict__ wv0, const float* __restrict__ wvr,
    const float* __restrict__ wor, const float* __restrict__ wo_last,
    float* __restrict__ scale_inv, float* __restrict__ biasv,
    bf16* __restrict__ wbf) {
  __shared__ int red[256];
  const int blk = blockIdx.x;
  const int tid = threadIdx.x;
  if (blk < 64) {
    int cnt = 0;
    for (int n = tid; n < 1024; n += 256) cnt += (L[blk * 1024 + n] >= 1) ? 1 : 0;
    red[tid] = cnt;
    __syncthreads();
    for (int s = 128; s > 0; s >>= 1) {
      if (tid < s) red[tid] += red[tid + s];
      __syncthreads();
    }
    if (tid == 0) {
      float iv = rsqrtf((float)red[0] + 1.0f);
      scale_inv[blk] = iv;
      biasv[blk] = fmaxf(0.0f, 128.0f * iv * LOG2E - 80.0f);
    }
  } else {
    for (int i = (blk - 64) * 256 + tid; i < 163840; i += 64 * 256) {
      float v;
      if      (i <   8192) v = wq0[i];
      else if (i <  40960) v = wqr[i - 8192];
      else if (i <  49152) v = wk0[i - 40960];
      else if (i <  81920) v = wkr[i - 49152];
      else if (i <  90112) v = wv0[i - 81920];
      else if (i < 122880) v = wvr[i - 90112];
      else if (i < 155648) v = wor[i - 122880];
      else                 v = wo_last[i - 155648];
      wbf[i] = (bf16)v;
    }
  }
}

// ------------- xk0: transpose x tile + layer-0 K/V for same tokens ---------
__global__ __launch_bounds__(256) void xk0_kernel(
    const float* __restrict__ x, const bf16* __restrict__ Wk,
    const bf16* __restrict__ Wv, bf16* __restrict__ xT,
    bf16* __restrict__ Kt, bf16* __restrict__ Vn) {
  __shared__ float tile[64][65];
  __shared__ __attribute__((aligned(16))) bf16 inp_lds[64 * 72];
  const int tid = threadIdx.x;
  const int lane = tid & 63, wv = tid >> 6;
  const int la = lane & 31, hi = lane >> 5;
  const int b = blockIdx.x >> 4;
  const int t0 = (blockIdx.x & 15) * 64;

  {
    const int nl = tid & 63, dbase = (tid >> 6) * 16;
#pragma unroll
    for (int i = 0; i < 16; i++) {
      int d = dbase + i;
      tile[d][nl] = x[(size_t)(b * 64 + d) * 1024 + t0 + nl];
    }
  }
  __syncthreads();
  {
    const int dl = (tid & 31) * 2, nb = (tid >> 5) * 8;
#pragma unroll
    for (int i = 0; i < 8; i++) {
      int n = nb + i;
      bf16x2 pr = {(bf16)tile[dl][n], (bf16)tile[dl + 1][n]};
      *(bf16x2*)(xT + (size_t)(b * 1024 + t0 + n) * 64 + dl) = pr;
      *(bf16x2*)&inp_lds[n * 72 + dl] = pr;
    }
  }
  __syncthreads();

  const int sub = wv & 1;
  if (wv < 2) {
#pragma unroll
    for (int rt2 = 0; rt2 < 2; rt2++) {
      const int rt = 2 * sub + rt2;
      bf16x8 wf[4];
#pragma unroll
      for (int ks = 0; ks < 4; ks++)
        wf[ks] = *(const bf16x8*)(Wk + (size_t)(la + 32 * rt) * 64 + hi * 8 + ks * 16);
#pragma unroll
      for (int tt = 0; tt < 2; tt++) {
        f32x16 acc = ZERO16;
#pragma unroll
        for (int ks = 0; ks < 4; ks++) {
          bf16x8 bfr = *(const bf16x8*)&inp_lds[(la + 32 * tt) * 72 + hi * 8 + ks * 16];
          acc = MFMA32(wf[ks], bfr, acc);
        }
#pragma unroll
        for (int g = 0; g < 4; g++) {
          bf16x4 pk;
#pragma unroll
          for (int i = 0; i < 4; i++) pk[i] = (bf16)fast_sigmoid(acc[4 * g + i]);
          *(bf16x4*)(Kt + (size_t)(b * 1024 + t0 + 32 * tt + la) * 128 +
                     32 * rt + 8 * g + 4 * hi) = pk;
        }
      }
    }
  } else {
#pragma unroll
    for (int rc2 = 0; rc2 < 2; rc2++) {
      const int rc = 2 * sub + rc2;
      bf16x8 wf[4];
#pragma unroll
      for (int ks = 0; ks < 4; ks++)
        wf[ks] = *(const bf16x8*)(Wv + (size_t)(la + 32 * rc) * 64 + hi * 8 + ks * 16);
#pragma unroll
      for (int tt = 0; tt < 2; tt++) {
        f32x16 acc = ZERO16;
#pragma unroll
        for (int ks = 0; ks < 4; ks++) {
          bf16x8 afr = *(const bf16x8*)&inp_lds[(la + 32 * tt) * 72 + hi * 8 + ks * 16];
          acc = MFMA32(afr, wf[ks], acc);
        }
#pragma unroll
        for (int g = 0; g < 4; g++) {
          bf16x4 pk;
#pragma unroll
          for (int i = 0; i < 4; i++) pk[i] = (bf16)fast_sigmoid(acc[4 * g + i]);
          *(bf16x4*)(Vn + (size_t)(b * 128 + la + 32 * rc) * 1024 +
                     t0 + 32 * tt + 8 * g + 4 * hi) = pk;
        }
      }
    }
  }
}

// -------- standalone KV producer (fallback path only), 64 tokens/block -----
template <int DIN>
__global__ __launch_bounds__(256) void kv_kernel(
    const bf16* __restrict__ inpT, const bf16* __restrict__ Wk,
    const bf16* __restrict__ Wv, bf16* __restrict__ Kt,
    bf16* __restrict__ Vn) {
  constexpr int SIN = DIN + 8;
  constexpr int KS = DIN / 16;
  constexpr int CPR = DIN / 8;
  __shared__ __attribute__((aligned(16))) bf16 inp_lds[64 * SIN];
  const int tid = threadIdx.x;
  const int lane = tid & 63, wv = tid >> 6;
  const int la = lane & 31, hi = lane >> 5;
  const int b = blockIdx.x >> 4;
  const int t0 = (blockIdx.x & 15) * 64;

  for (int i = tid; i < 64 * CPR; i += 256) {
    int row = i / CPR, c = i % CPR;
    *(bf16x8*)&inp_lds[row * SIN + c * 8] =
        *(const bf16x8*)(inpT + (size_t)(b * 1024 + t0 + row) * DIN + c * 8);
  }
  __syncthreads();

  const int sub = wv & 1;
  if (wv < 2) {
#pragma unroll
    for (int rt2 = 0; rt2 < 2; rt2++) {
      const int rt = 2 * sub + rt2;
      bf16x8 wf[KS];
#pragma unroll
      for (int ks = 0; ks < KS; ks++)
        wf[ks] = *(const bf16x8*)(Wk + (size_t)(la + 32 * rt) * DIN + hi * 8 + ks * 16);
#pragma unroll
      for (int tt = 0; tt < 2; tt++) {
        f32x16 acc = ZERO16;
#pragma unroll
        for (int ks = 0; ks < KS; ks++) {
          bf16x8 bfr = *(const bf16x8*)&inp_lds[(la + 32 * tt) * SIN + hi * 8 + ks * 16];
          acc = MFMA32(wf[ks], bfr, acc);
        }
#pragma unroll
        for (int g = 0; g < 4; g++) {
          bf16x4 pk;
#pragma unroll
          for (int i = 0; i < 4; i++) pk[i] = (bf16)fast_sigmoid(acc[4 * g + i]);
          *(bf16x4*)(Kt + (size_t)(b * 1024 + t0 + 32 * tt + la) * 128 +
                     32 * rt + 8 * g + 4 * hi) = pk;
        }
      }
    }
  } else {
#pragma unroll
    for (int rc2 = 0; rc2 < 2; rc2++) {
      const int rc = 2 * sub + rc2;
      bf16x8 wf[KS];
#pragma unroll
      for (int ks = 0; ks < KS; ks++)
        wf[ks] = *(const bf16x8*)(Wv + (size_t)(la + 32 * rc) * DIN + hi * 8 + ks * 16);
#pragma unroll
      for (int tt = 0; tt < 2; tt++) {
        f32x16 acc = ZERO16;
#pragma unroll
        for (int ks = 0; ks < KS; ks++) {
          bf16x8 afr = *(const bf16x8*)&inp_lds[(la + 32 * tt) * SIN + hi * 8 + ks * 16];
          acc = MFMA32(afr, wf[ks], acc);
        }
#pragma unroll
        for (int g = 0; g < 4; g++) {
          bf16x4 pk;
#pragma unroll
          for (int i = 0; i < 4; i++) pk[i] = (bf16)fast_sigmoid(acc[4 * g + i]);
          *(bf16x4*)(Vn + (size_t)(b * 128 + la + 32 * rc) * 1024 +
                     t0 + 32 * tt + 8 * g + 4 * hi) = pk;
        }
      }
    }
  }
}

// ---------------- flash: Q-gen + attention + projection (+ next K/V) -------
// Block: 128 Q rows, 16 KV tiles of 64, 4 waves, 2 blocks/CU (grid 512).
// XCD swizzle: x=blockIdx&7 (XCD via round-robin), k=blockIdx>>3;
// b = x*8 + (k&7), q0 = (k>>3)*128 -> one batch's 8 q-blocks share an XCD.
template <int DIN>
__global__ __launch_bounds__(256, 2) void flash_kernel(
    const bf16* __restrict__ inpT, const bf16* __restrict__ Wq,
    const bf16* __restrict__ Kt, const bf16* __restrict__ Vn,
    const float* __restrict__ scale_inv, const float* __restrict__ biasv,
    const int* __restrict__ L, const bf16* __restrict__ Wo,
    void* __restrict__ outp, int last,
    const bf16* __restrict__ Wkn, const bf16* __restrict__ Wvn,
    bf16* __restrict__ Ktn, bf16* __restrict__ Vnn, int kvgen) {
  // loop:     [0,17408) K 64x136 | [17408,35840) V 128x72 | [35840,54272) P 128x72
  // prologue: inp 128x(DIN+8)@0 | Q_lds 128x136 @35840
  // epilogue: rsp f32[2][128]@0 (pre-F) | O_lds 128x136 @35840 | O2 128x136 @0
  __shared__ __attribute__((aligned(16))) char smem[70656];
  bf16* K_lds = (bf16*)smem;
  bf16* V_lds = (bf16*)(smem + 17408);
  bf16* P_lds = (bf16*)(smem + 35840);

  const int tid = threadIdx.x;
  const int lane = tid & 63, wv = tid >> 6;
  const int la = lane & 31, hi = lane >> 5;
  const int xcd = blockIdx.x & 7;
  const int kk = blockIdx.x >> 3;
  const int b = xcd * 8 + (kk & 7);
  const int q0 = (kk >> 3) * 128;

  const float inv2 = scale_inv[b] * LOG2E;
  const float bb = biasv[b];

  // ---- prologue: stage inp (128 x DIN), Q' = sigmoid(inp Wq^T) * inv2 ----
  {
    constexpr int SIN = DIN + 8;
    constexpr int KSD = DIN / 16;
    constexpr int CPR = DIN / 8;
    bf16* inp_s = (bf16*)smem;
    for (int i = tid; i < 128 * CPR; i += 256) {
      int row = i / CPR, c = i % CPR;
      *(bf16x8*)&inp_s[row * SIN + c * 8] =
          *(const bf16x8*)(inpT + (size_t)(b * 1024 + q0 + row) * DIN + c * 8);
    }
    __syncthreads();
    bf16* Q_lds = (bf16*)(smem + 35840);
    bf16x8 wf[KSD];
#pragma unroll
    for (int ks = 0; ks < KSD; ks++)
      wf[ks] = *(const bf16x8*)(Wq + (size_t)(la + 32 * wv) * DIN + hi * 8 + ks * 16);
#pragma unroll
    for (int nt = 0; nt < 4; nt++) {
      f32x16 acc = ZERO16;
#pragma unroll
      for (int ks = 0; ks < KSD; ks++) {
        bf16x8 bfr = *(const bf16x8*)&inp_s[(la + 32 * nt) * SIN + hi * 8 + ks * 16];
        acc = MFMA32(wf[ks], bfr, acc);
      }
#pragma unroll
      for (int g = 0; g < 4; g++) {
        bf16x4 pk;
#pragma unroll
        for (int i = 0; i < 4; i++)
          pk[i] = (bf16)(fast_sigmoid(acc[4 * g + i]) * inv2);
        *(bf16x4*)&Q_lds[(size_t)(32 * nt + la) * 136 + 32 * wv + 8 * g + 4 * hi] = pk;
      }
    }
    __syncthreads();
  }

  const int ms = wv & 1, nw = wv >> 1;
  bf16x8 qB[2][8];
#pragma unroll
  for (int nt = 0; nt < 2; nt++)
#pragma unroll
    for (int ks = 0; ks < 8; ks++)
      qB[nt][ks] = *(const bf16x8*)((bf16*)(smem + 35840) +
                                    (size_t)(64 * nw + 32 * nt + la) * 136 +
                                    hi * 8 + ks * 16);

  const int krow = tid >> 4, kc = (tid & 15) * 8;
  const int vrow = tid >> 3, vc = (tid & 7) * 8;
  const bf16* kbase = Kt + (size_t)b * 1024 * 128;
  const bf16* vbase = Vn + (size_t)b * 128 * 1024;
  bf16x8 kr[4], vr[4];
#pragma unroll
  for (int p = 0; p < 4; p++) {
    kr[p] = *(const bf16x8*)(kbase + (size_t)(krow + 16 * p) * 128 + kc);
    vr[p] = *(const bf16x8*)(vbase + (size_t)(vrow + 32 * p) * 1024 + vc);
  }

  const int nh = wv & 1, rh = wv >> 1;
  f32x16 acc_o[2][2] = {{ZERO16, ZERO16}, {ZERO16, ZERO16}};
  float rs[2] = {0.f, 0.f};

  for (int it = 0; it < 16; it++) {
    __syncthreads();  // (A)
#pragma unroll
    for (int p = 0; p < 4; p++)
      *(bf16x8*)&K_lds[(krow + 16 * p) * 136 + kc] = kr[p];
#pragma unroll
    for (int p = 0; p < 4; p++)
      *(bf16x8*)&V_lds[(vrow + 32 * p) * 72 + vc] = vr[p];
    __syncthreads();  // (B)

    if (it < 15) {
      const int m1 = (it + 1) * 64;
#pragma unroll
      for (int p = 0; p < 4; p++) {
        kr[p] = *(const bf16x8*)(kbase + (size_t)(m1 + krow + 16 * p) * 128 + kc);
        vr[p] = *(const bf16x8*)(vbase + (size_t)(vrow + 32 * p) * 1024 + m1 + vc);
      }
    }

    bf16x8 kf[8];
#pragma unroll
    for (int ks = 0; ks < 8; ks++)
      kf[ks] = *(const bf16x8*)&K_lds[(32 * ms + la) * 136 + hi * 8 + ks * 16];
#pragma unroll
    for (int nt = 0; nt < 2; nt++) {
      f32x16 sa = ZERO16;
#pragma unroll
      for (int ks = 0; ks < 8; ks++) sa = MFMA32(kf[ks], qB[nt][ks], sa);
#pragma unroll
      for (int g = 0; g < 4; g++) {
        bf16x4 pk;
#pragma unroll
        for (int i = 0; i < 4; i++) {
          float p = fast_exp2(sa[4 * g + i] - bb);
          rs[nt] += p;
          pk[i] = (bf16)p;
        }
        *(bf16x4*)&P_lds[(size_t)(64 * nw + 32 * nt + la) * 72 +
                         32 * ms + 8 * g + 4 * hi] = pk;
      }
    }
    __syncthreads();  // (C)

    bf16x8 pA[2][4];
#pragma unroll
    for (int nt2 = 0; nt2 < 2; nt2++)
#pragma unroll
      for (int k2 = 0; k2 < 4; k2++)
        pA[nt2][k2] = *(const bf16x8*)&P_lds[(size_t)(64 * nh + 32 * nt2 + la) * 72 +
                                             hi * 8 + k2 * 16];
#pragma unroll
    for (int rt = 0; rt < 2; rt++) {
#pragma unroll
      for (int k2 = 0; k2 < 4; k2++) {
        bf16x8 vB = *(const bf16x8*)&V_lds[(size_t)(64 * rh + 32 * rt + la) * 72 +
                                           hi * 8 + k2 * 16];
        acc_o[0][rt] = MFMA32(pA[0][k2], vB, acc_o[0][rt]);
        acc_o[1][rt] = MFMA32(pA[1][k2], vB, acc_o[1][rt]);
      }
    }
  }

  // ---- epilogue: rowsums, normalize, project ----
  rs[0] += __shfl_xor(rs[0], 32, 64);
  rs[1] += __shfl_xor(rs[1], 32, 64);
  __syncthreads();  // (D)
  float* rsp = (float*)smem;
  if (lane < 32) {
    rsp[ms * 128 + 64 * nw + la] = rs[0];
    rsp[ms * 128 + 64 * nw + 32 + la] = rs[1];
  }
  __syncthreads();  // (E)

  bf16* O_lds = (bf16*)(smem + 35840);
#pragma unroll
  for (int nt2 = 0; nt2 < 2; nt2++) {
#pragma unroll
    for (int g = 0; g < 4; g++) {
      const int nb = 64 * nh + 32 * nt2 + 8 * g + 4 * hi;
      f32x4 ra = *(f32x4*)&rsp[nb];
      f32x4 rc = *(f32x4*)&rsp[128 + nb];
      f32x4 is;
#pragma unroll
      for (int i = 0; i < 4; i++) is[i] = 1.0f / (ra[i] + rc[i]);
#pragma unroll
      for (int rt = 0; rt < 2; rt++) {
#pragma unroll
        for (int i = 0; i < 4; i++) {
          O_lds[(size_t)(nb + i) * 136 + 64 * rh + 32 * rt + la] =
              (bf16)(acc_o[nt2][rt][4 * g + i] * is[i]);
        }
      }
    }
  }
  __syncthreads();  // (F)

  if (!last) {
    bf16* out_b = (bf16*)outp;
    bf16* O2 = (bf16*)smem;  // post-silu tokens, token-major (rsp dead after F)
    const int* Lg = L + b * 1024 + q0;
    bf16x8 wB[8];
#pragma unroll
    for (int ks = 0; ks < 8; ks++)
      wB[ks] = *(const bf16x8*)(Wo + (size_t)(la + 32 * wv) * 128 + hi * 8 + ks * 16);
#pragma unroll
    for (int nt = 0; nt < 4; nt++) {
      f32x16 acc = ZERO16;
#pragma unroll
      for (int ks = 0; ks < 8; ks++) {
        bf16x8 oA = *(const bf16x8*)&O_lds[(size_t)(la + 32 * nt) * 136 +
                                           hi * 8 + ks * 16];
        acc = MFMA32(oA, wB[ks], acc);
      }
#pragma unroll
      for (int g = 0; g < 4; g++) {
#pragma unroll
        for (int i = 0; i < 4; i++) {
          int n = 32 * nt + 8 * g + 4 * hi + i;
          float xv = acc[4 * g + i];
          float y = xv * fast_sigmoid(xv) * (float)Lg[n];
          out_b[(size_t)(b * 1024 + q0 + n) * 128 + 32 * wv + la] = (bf16)y;
          if (kvgen) O2[(size_t)n * 136 + 32 * wv + la] = (bf16)y;
        }
      }
    }
    if (kvgen) {
      __syncthreads();  // (G) O2 complete
      const bf16* O2c = (const bf16*)smem;
      const int sub = wv & 1;
      const bf16* W2 = (wv < 2) ? Wkn : Wvn;
#pragma unroll
      for (int rt2 = 0; rt2 < 2; rt2++) {
        const int rt = 2 * sub + rt2;
        bf16x8 wf[8];
#pragma unroll
        for (int ks = 0; ks < 8; ks++)
          wf[ks] = *(const bf16x8*)(W2 + (size_t)(la + 32 * rt) * 128 +
                                    hi * 8 + ks * 16);
#pragma unroll
        for (int tt = 0; tt < 4; tt++) {
          f32x16 acc = ZERO16;
          if (wv < 2) {
#pragma unroll
            for (int ks = 0; ks < 8; ks++) {
              bf16x8 bB = *(const bf16x8*)&O2c[(size_t)(32 * tt + la) * 136 +
                                               hi * 8 + ks * 16];
              acc = MFMA32(wf[ks], bB, acc);
            }
#pragma unroll
            for (int g = 0; g < 4; g++) {
              bf16x4 pk;
#pragma unroll
              for (int i = 0; i < 4; i++) pk[i] = (bf16)fast_sigmoid(acc[4 * g + i]);
              *(bf16x4*)(Ktn + (size_t)(b * 1024 + q0 + 32 * tt + la) * 128 +
                         32 * rt + 8 * g + 4 * hi) = pk;
            }
          } else {
#pragma unroll
            for (int ks = 0; ks < 8; ks++) {
              bf16x8 aA = *(const bf16x8*)&O2c[(size_t)(32 * tt + la) * 136 +
                                               hi * 8 + ks * 16];
              acc = MFMA32(aA, wf[ks], acc);
            }
#pragma unroll
            for (int g = 0; g < 4; g++) {
              bf16x4 pk;
#pragma unroll
              for (int i = 0; i < 4; i++) pk[i] = (bf16)fast_sigmoid(acc[4 * g + i]);
              *(bf16x4*)(Vnn + (size_t)(b * 128 + 32 * rt + la) * 1024 +
                         q0 + 32 * tt + 8 * g + 4 * hi) = pk;
            }
          }
        }
      }
    }
  } else {
    const int hs = wv & 1, nq = wv >> 1;
    float* outf = (float*)outp;
    bf16x8 wA[8];
#pragma unroll
    for (int ks = 0; ks < 8; ks++)
      wA[ks] = *(const bf16x8*)(Wo + (size_t)(la + 32 * hs) * 128 + hi * 8 + ks * 16);
#pragma unroll
    for (int t = 0; t < 2; t++) {
      const int ns4 = nq + 2 * t;
      f32x16 acc = ZERO16;
#pragma unroll
      for (int ks = 0; ks < 8; ks++) {
        bf16x8 oB = *(const bf16x8*)&O_lds[(size_t)(32 * ns4 + la) * 136 +
                                           hi * 8 + ks * 16];
        acc = MFMA32(wA[ks], oB, acc);
      }
#pragma unroll
      for (int g = 0; g < 4; g++) {
#pragma unroll
        for (int i = 0; i < 4; i++) {
          int h = 32 * hs + 8 * g + 4 * hi + i;
          float xv = acc[4 * g + i];
          outf[(size_t)(b * 64 + h) * 1024 + q0 + 32 * ns4 + la] =
              xv * fast_sigmoid(xv);
        }
      }
    }
  }
}

// ---------------- transpose x (fallback path) ------------------------------
__global__ __launch_bounds__(256) void xpose_kernel(const float* __restrict__ x,
                                                    bf16* __restrict__ xT) {
  __shared__ float tile[64][65];
  const int blk = blockIdx.x;
  const int b = blk >> 4;
  const int n0 = (blk & 15) * 64;
  const int tid = threadIdx.x;
  {
    const int nl = tid & 63, dbase = (tid >> 6) * 16;
#pragma unroll
    for (int i = 0; i < 16; i++) {
      int d = dbase + i;
      tile[d][nl] = x[(size_t)(b * 64 + d) * 1024 + n0 + nl];
    }
  }
  __syncthreads();
  {
    const int dl = (tid & 31) * 2, nb = (tid >> 5) * 8;
#pragma unroll
    for (int i = 0; i < 8; i++) {
      int n = nb + i;
      bf16x2 pr = {(bf16)tile[dl][n], (bf16)tile[dl + 1][n]};
      *(bf16x2*)(xT + (size_t)(b * 1024 + n0 + n) * 64 + dl) = pr;
    }
  }
}

// ---------------- host launch ----------------
extern "C" void kernel_launch(void* const* d_in, const int* in_sizes, int n_in,
                              void* d_out, int out_size, void* d_ws, size_t ws_size,
                              hipStream_t stream) {
  const float* x = (const float*)d_in[0];
  const int* L = (const int*)d_in[1];
  const float* wq0 = (const float*)d_in[2];
  const float* wqr = (const float*)d_in[3];
  const float* wk0 = (const float*)d_in[4];
  const float* wkr = (const float*)d_in[5];
  const float* wv0 = (const float*)d_in[6];
  const float* wvr = (const float*)d_in[7];
  const float* wor = (const float*)d_in[8];
  const float* wo_last = (const float*)d_in[9];

  char* ws = (char*)d_ws;
  float* scale_inv = (float*)(ws + 0);
  float* biasv = (float*)(ws + 1024);
  bf16* wbf = (bf16*)(ws + 4096);
  bf16* xT = (bf16*)(ws + 335872);
  bf16* inpT = (bf16*)(ws + 8724480);
  bf16* KtA = (bf16*)(ws + 25501696);
  bf16* VnA = (bf16*)(ws + 42278912);
  bf16* KtB = (bf16*)(ws + 59056128);
  bf16* VnB = (bf16*)(ws + 75833344);
  // bf16 weight offsets: wq0@0 wqr@8192 wk0@40960 wkr@49152 wv0@81920
  //                      wvr@90112 wor@122880 wo_last@155648

  prep_kernel<<<128, 256, 0, stream>>>(L, wq0, wqr, wk0, wkr, wv0, wvr, wor,
                                       wo_last, scale_inv, biasv, wbf);

  if (ws_size >= 92610560) {
    xk0_kernel<<<1024, 256, 0, stream>>>(x, wbf + 40960, wbf + 81920, xT, KtA, VnA);
    flash_kernel<64><<<512, 256, 0, stream>>>(
        xT, wbf + 0, KtA, VnA, scale_inv, biasv, L, wbf + 122880, (void*)inpT, 0,
        wbf + 49152, wbf + 90112, KtB, VnB, 1);
    flash_kernel<128><<<512, 256, 0, stream>>>(
        inpT, wbf + 8192, KtB, VnB, scale_inv, biasv, L, wbf + 139264,
        (void*)inpT, 0, wbf + 65536, wbf + 106496, KtA, VnA, 1);
    flash_kernel<128><<<512, 256, 0, stream>>>(
        inpT, wbf + 24576, KtA, VnA, scale_inv, biasv, L, wbf + 155648, d_out, 1,
        nullptr, nullptr, nullptr, nullptr, 0);
  } else if (ws_size >= 59056128) {
    xpose_kernel<<<1024, 256, 0, stream>>>(x, xT);
    for (int l = 0; l < 3; l++) {
      const bf16* Wq = (l == 0) ? wbf + 0 : wbf + 8192 + (size_t)(l - 1) * 16384;
      const bf16* Wk = (l == 0) ? wbf + 40960 : wbf + 49152 + (size_t)(l - 1) * 16384;
      const bf16* Wv = (l == 0) ? wbf + 81920 : wbf + 90112 + (size_t)(l - 1) * 16384;
      const bf16* Wo = (l < 2) ? wbf + 122880 + (size_t)l * 16384 : wbf + 155648;
      void* outp = (l < 2) ? (void*)inpT : (void*)d_out;
      if (l == 0) {
        kv_kernel<64><<<1024, 256, 0, stream>>>(xT, Wk, Wv, KtA, VnA);
        flash_kernel<64><<<512, 256, 0, stream>>>(xT, Wq, KtA, VnA, scale_inv,
                                                  biasv, L, Wo, outp, 0,
                                                  nullptr, nullptr, nullptr,
                                                  nullptr, 0);
      } else {
        kv_kernel<128><<<1024, 256, 0, stream>>>(inpT, Wk, Wv, KtA, VnA);
        flash_kernel<128><<<512, 256, 0, stream>>>(inpT, Wq, KtA, VnA, scale_inv,
                                                   biasv, L, Wo, outp,
                                                   (l == 2) ? 1 : 0, nullptr,
                                                   nullptr, nullptr, nullptr, 0);
      }
    }
  }
}